// Round 9
// baseline (437.312 us; speedup 1.0000x reference)
//
#include <hip/hip_runtime.h>
#include <cstdint>
#include <cstddef>

#define MI_NN 16384
#define DIS_NN 8192
#define EMB 128
#define EMM (MI_NN*32)
#define EDD (DIS_NN*32)

typedef __attribute__((ext_vector_type(8))) short short8;
typedef __attribute__((ext_vector_type(4))) float f32x4;

__device__ __forceinline__ float leakyr(float x){ return x > 0.f ? x : 0.2f*x; }
__device__ __forceinline__ float eluf(float x){ return x > 0.f ? x : expm1f(x); }

__device__ __forceinline__ unsigned bf16u(float x){
  unsigned u = __float_as_uint(x);
  return (u + 0x7FFFu + ((u >> 16) & 1u)) >> 16;   // RNE
}
__device__ __forceinline__ float bfl(unsigned p){ return __uint_as_float(p << 16); }
__device__ __forceinline__ float bfh(unsigned p){ return __uint_as_float(p & 0xFFFF0000u); }

// ================= CSR build (merged MM+DD) =================
__global__ __launch_bounds__(256) void k_count2g(const int* __restrict__ c0, int* __restrict__ n0c,
                                                 int E0, int nb0,
                                                 const int* __restrict__ c1, int* __restrict__ n1c,
                                                 int E1, unsigned* __restrict__ ctr){
  if (blockIdx.x == 0 && threadIdx.x == 0) ctr[0] = 0u;   // reset pass0 done-counter
  int b = blockIdx.x;
  const int* col; int* cnt; int E; int t;
  if (b < nb0){ col = c0; cnt = n0c; E = E0; t = b*256 + threadIdx.x; }
  else        { col = c1; cnt = n1c; E = E1; t = (b - nb0)*256 + threadIdx.x; }
  if (t < E) atomicAdd(&cnt[col[t]], 1);
}

__global__ __launch_bounds__(1024) void k_scan2g(const int* __restrict__ cnt0, int* __restrict__ rp0,
                                                 int n0, int E0,
                                                 const int* __restrict__ cnt1, int* __restrict__ rp1,
                                                 int n1, int E1){
  const int* cnt = blockIdx.x ? cnt1 : cnt0;
  int* rowptr    = blockIdx.x ? rp1  : rp0;
  int n          = blockIdx.x ? n1   : n0;
  int E          = blockIdx.x ? E1   : E0;
  __shared__ int lds[1024];
  int t = threadIdx.x;
  int chunk = n >> 10;
  int base = t*chunk;
  int s = 0;
  for (int i = 0; i < chunk; ++i) s += cnt[base+i];
  lds[t] = s; __syncthreads();
  for (int off = 1; off < 1024; off <<= 1){
    int v = (t >= off) ? lds[t-off] : 0;
    __syncthreads();
    lds[t] += v;
    __syncthreads();
  }
  int run = lds[t] - s;
  for (int i = 0; i < chunk; ++i){ rowptr[base+i] = run; run += cnt[base+i]; }
  if (t == 0) rowptr[n] = E;
}

__global__ __launch_bounds__(256) void k_fill2g(
    const int* __restrict__ r0a, const int* __restrict__ c0a, const float* __restrict__ w0a,
    const int* __restrict__ rp0, int* __restrict__ f0, int2* __restrict__ e0,
    int E0, int nb0,
    const int* __restrict__ r1a, const int* __restrict__ c1a, const float* __restrict__ w1a,
    const int* __restrict__ rp1, int* __restrict__ f1, int2* __restrict__ e1,
    int E1){
  int b = blockIdx.x;
  const int *row, *col; const float* ew; const int* rowptr;
  int* fill; int2* epk; int E, t;
  if (b < nb0){ row=r0a; col=c0a; ew=w0a; rowptr=rp0; fill=f0; epk=e0; E=E0; t=b*256+threadIdx.x; }
  else        { row=r1a; col=c1a; ew=w1a; rowptr=rp1; fill=f1; epk=e1; E=E1; t=(b-nb0)*256+threadIdx.x; }
  if (t < E){
    int c = col[t];
    int p = rowptr[c] + atomicAdd(&fill[c], 1);
    epk[p] = make_int2(row[t], __float_as_int(ew[t]));
  }
}

// ================= dense h = x @ w (fp32, bf16 out); FUSE=1 adds GAT src/dst scores =================
template<int FUSE>
__global__ __launch_bounds__(256) void k_gemm2g(
    const float* __restrict__ X0, const float* __restrict__ W0, ushort* __restrict__ H0, int nb0,
    const float* __restrict__ X1, const float* __restrict__ W1, ushort* __restrict__ H1,
    const float* __restrict__ as0, const float* __restrict__ ad0,
    float* __restrict__ es0, float* __restrict__ ed0,
    const float* __restrict__ as1, const float* __restrict__ ad1,
    float* __restrict__ es1, float* __restrict__ ed1){
  int b = blockIdx.x;
  const float *X, *W, *asr, *ads; ushort* H; float *es, *ed; int rb;
  if (b < nb0){ X=X0; W=W0; H=H0; asr=as0; ads=ad0; es=es0; ed=ed0; rb = b; }
  else        { X=X1; W=W1; H=H1; asr=as1; ads=ad1; es=es1; ed=ed1; rb = b - nb0; }
  __shared__ float wl[EMB*EMB];
  int t = threadIdx.x;
  {
    const float4* W4 = (const float4*)W;
    float4* L4 = (float4*)wl;
    #pragma unroll
    for (int i = 0; i < 16; ++i) L4[t + 256*i] = W4[t + 256*i];
  }
  __syncthreads();
  int jg = t & 31;
  int rg = t >> 5;
  int r0 = rb*32 + rg*4;
  f32x4 acc0 = {0,0,0,0}, acc1 = {0,0,0,0}, acc2 = {0,0,0,0}, acc3 = {0,0,0,0};
  const float4* X4 = (const float4*)X;
  for (int k4 = 0; k4 < 32; ++k4){
    float4 x0 = X4[(size_t)(r0+0)*32 + k4];
    float4 x1 = X4[(size_t)(r0+1)*32 + k4];
    float4 x2 = X4[(size_t)(r0+2)*32 + k4];
    float4 x3 = X4[(size_t)(r0+3)*32 + k4];
#define GSTEP(c0,c1,c2,c3,kq) { f32x4 w4 = *(const f32x4*)&wl[(kq)*EMB + jg*4]; \
      acc0 += (c0)*w4; acc1 += (c1)*w4; acc2 += (c2)*w4; acc3 += (c3)*w4; }
    GSTEP(x0.x, x1.x, x2.x, x3.x, k4*4+0)
    GSTEP(x0.y, x1.y, x2.y, x3.y, k4*4+1)
    GSTEP(x0.z, x1.z, x2.z, x3.z, k4*4+2)
    GSTEP(x0.w, x1.w, x2.w, x3.w, k4*4+3)
#undef GSTEP
  }
#define PACK2(o, a) { o.x = bf16u(a[0]) | (bf16u(a[1])<<16); o.y = bf16u(a[2]) | (bf16u(a[3])<<16); }
  uint2 o0, o1, o2, o3;
  PACK2(o0, acc0) PACK2(o1, acc1) PACK2(o2, acc2) PACK2(o3, acc3)
#undef PACK2
  ushort* out = H + (size_t)r0*EMB + jg*4;
  *(uint2*)(out)         = o0;
  *(uint2*)(out + EMB)   = o1;
  *(uint2*)(out + 2*EMB) = o2;
  *(uint2*)(out + 3*EMB) = o3;

  if (FUSE){
    f32x4 s4 = *(const f32x4*)&asr[jg*4];
    f32x4 d4 = *(const f32x4*)&ads[jg*4];
    float ps0 = acc0[0]*s4[0] + acc0[1]*s4[1] + acc0[2]*s4[2] + acc0[3]*s4[3];
    float ps1 = acc1[0]*s4[0] + acc1[1]*s4[1] + acc1[2]*s4[2] + acc1[3]*s4[3];
    float ps2 = acc2[0]*s4[0] + acc2[1]*s4[1] + acc2[2]*s4[2] + acc2[3]*s4[3];
    float ps3 = acc3[0]*s4[0] + acc3[1]*s4[1] + acc3[2]*s4[2] + acc3[3]*s4[3];
    float pd0 = acc0[0]*d4[0] + acc0[1]*d4[1] + acc0[2]*d4[2] + acc0[3]*d4[3];
    float pd1 = acc1[0]*d4[0] + acc1[1]*d4[1] + acc1[2]*d4[2] + acc1[3]*d4[3];
    float pd2 = acc2[0]*d4[0] + acc2[1]*d4[1] + acc2[2]*d4[2] + acc2[3]*d4[3];
    float pd3 = acc3[0]*d4[0] + acc3[1]*d4[1] + acc3[2]*d4[2] + acc3[3]*d4[3];
    #pragma unroll
    for (int off = 16; off; off >>= 1){
      ps0 += __shfl_xor(ps0, off); ps1 += __shfl_xor(ps1, off);
      ps2 += __shfl_xor(ps2, off); ps3 += __shfl_xor(ps3, off);
      pd0 += __shfl_xor(pd0, off); pd1 += __shfl_xor(pd1, off);
      pd2 += __shfl_xor(pd2, off); pd3 += __shfl_xor(pd3, off);
    }
    if (jg == 0){
      es[r0+0] = ps0; es[r0+1] = ps1; es[r0+2] = ps2; es[r0+3] = ps3;
      ed[r0+0] = pd0; ed[r0+1] = pd1; ed[r0+2] = pd2; ed[r0+3] = pd3;
    }
  }
}

// ================= degree: DEG1 + DEG2, both graphs =================
__global__ __launch_bounds__(256) void k_deg2g(
    const int* __restrict__ rp0, const int2* __restrict__ ep0,
    float* __restrict__ d10, float* __restrict__ d20, int n0, int nb0,
    const int* __restrict__ rp1, const int2* __restrict__ ep1,
    float* __restrict__ d11, float* __restrict__ d21, int n1){
  int b = blockIdx.x;
  const int* rowptr; const int2* epk; float *d1, *d2; int n, wid;
  int lane = threadIdx.x & 63;
  if (b < nb0){ rowptr=rp0; epk=ep0; d1=d10; d2=d20; n=n0; wid = (b*256 + threadIdx.x) >> 6; }
  else        { rowptr=rp1; epk=ep1; d1=d11; d2=d21; n=n1; wid = ((b-nb0)*256 + threadIdx.x) >> 6; }
  if (wid >= n) return;
  int beg = rowptr[wid], end = rowptr[wid+1];
  float s = 0.f;
  for (int i = beg + lane; i < end; i += 64) s += __int_as_float(epk[i].y);
  #pragma unroll
  for (int off = 32; off; off >>= 1) s += __shfl_xor(s, off);
  if (lane == 0){
    d1[wid] = rsqrtf(1.0f + s);
    d2[wid] = rsqrtf(1.0f + (float)(end - beg));
  }
}

// ================= GCN aggregation: 8B/lane, 2 edges per wave =================
__global__ __launch_bounds__(256) void k_agg2g(
    const ushort* __restrict__ H0, const float* __restrict__ di0, const int* __restrict__ rp0,
    const int2* __restrict__ ep0, const float* __restrict__ bi0,
    float* __restrict__ xn0, float* __restrict__ fe0, int n0, int nb0,
    const ushort* __restrict__ H1, const float* __restrict__ di1, const int* __restrict__ rp1,
    const int2* __restrict__ ep1, const float* __restrict__ bi1,
    float* __restrict__ xn1, float* __restrict__ fe1, int n1,
    int useew, int femode){
  int b = blockIdx.x;
  const ushort* H; const float* dinv; const int* rowptr; const int2* epk;
  const float* bias; float* xnext; float* fea; int n, wid;
  int lane = threadIdx.x & 63;
  if (b < nb0){ H=H0; dinv=di0; rowptr=rp0; epk=ep0; bias=bi0; xnext=xn0; fea=fe0; n=n0;
                wid = (b*256 + threadIdx.x) >> 6; }
  else        { H=H1; dinv=di1; rowptr=rp1; epk=ep1; bias=bi1; xnext=xn1; fea=fe1; n=n1;
                wid = ((b-nb0)*256 + threadIdx.x) >> 6; }
  if (wid >= n) return;
  int v = wid;
  int half = lane >> 5;               // 0: even edges, 1: odd edges
  int hl   = lane & 31;               // 4-channel group: channels 4*hl..4*hl+3
  float dv = dinv[v];
  uint2 hv = *(const uint2*)(H + (size_t)v*EMB + hl*4);
  float a0, a1, a2, a3;
  if (half == 0){
    a0 = dv*bfl(hv.x); a1 = dv*bfh(hv.x); a2 = dv*bfl(hv.y); a3 = dv*bfh(hv.y);
  } else { a0 = a1 = a2 = a3 = 0.f; }
  int beg = rowptr[v], end = rowptr[v+1];
  int i = beg + half;
  for (; i + 2 < end; i += 4){
    int2 eA = epk[i], eB = epk[i+2];
    float nA = dinv[eA.x], nB = dinv[eB.x];
    if (useew){ nA *= __int_as_float(eA.y); nB *= __int_as_float(eB.y); }
    uint2 hA = *(const uint2*)(H + (size_t)eA.x*EMB + hl*4);
    uint2 hB = *(const uint2*)(H + (size_t)eB.x*EMB + hl*4);
    a0 += nA*bfl(hA.x) + nB*bfl(hB.x);
    a1 += nA*bfh(hA.x) + nB*bfh(hB.x);
    a2 += nA*bfl(hA.y) + nB*bfl(hB.y);
    a3 += nA*bfh(hA.y) + nB*bfh(hB.y);
  }
  if (i < end){
    int2 e = epk[i];
    float nm = dinv[e.x];
    if (useew) nm *= __int_as_float(e.y);
    uint2 h = *(const uint2*)(H + (size_t)e.x*EMB + hl*4);
    a0 += nm*bfl(h.x); a1 += nm*bfh(h.x); a2 += nm*bfl(h.y); a3 += nm*bfh(h.y);
  }
  // merge halves
  a0 += __shfl_xor(a0, 32); a1 += __shfl_xor(a1, 32);
  a2 += __shfl_xor(a2, 32); a3 += __shfl_xor(a3, 32);
  if (half == 0){
    float4 b4 = *(const float4*)(bias + hl*4);
    float o0 = eluf(dv*a0 + b4.x), o1 = eluf(dv*a1 + b4.y);
    float o2 = eluf(dv*a2 + b4.z), o3 = eluf(dv*a3 + b4.w);
    *(float4*)(xnext + (size_t)v*EMB + hl*4) = make_float4(o0, o1, o2, o3);
    float* fp = fea + (size_t)v*EMB + hl*4;
    if (femode == 0){
      *(float4*)fp = make_float4(o0, o1, o2, o3);
    } else {
      float4 f = *(float4*)fp;
      *(float4*)fp = make_float4(f.x + o0, f.y + o1, f.z + o2, f.w + o3);
    }
  }
}

// ================= GAT aggregation + bf16 shadow, 8B/lane feature pass =================
__global__ __launch_bounds__(256) void k_gat2g(
    const ushort* __restrict__ H0, const float* __restrict__ es0, const float* __restrict__ ed0,
    const int* __restrict__ rp0, const int2* __restrict__ ep0, const float* __restrict__ bi0,
    float* __restrict__ fe0, unsigned* __restrict__ sh0, int n0, int nb0,
    const ushort* __restrict__ H1, const float* __restrict__ es1, const float* __restrict__ ed1,
    const int* __restrict__ rp1, const int2* __restrict__ ep1, const float* __restrict__ bi1,
    float* __restrict__ fe1, unsigned* __restrict__ sh1, int n1){
  int b = blockIdx.x;
  const ushort* H; const float *es, *ed; const int* rowptr; const int2* epk; const float* bias;
  float* fea; unsigned* shadow; int n, wid;
  int lane = threadIdx.x & 63;
  if (b < nb0){ H=H0; es=es0; ed=ed0; rowptr=rp0; epk=ep0; bias=bi0; fea=fe0; shadow=sh0; n=n0;
                wid = (b*256 + threadIdx.x) >> 6; }
  else        { H=H1; es=es1; ed=ed1; rowptr=rp1; epk=ep1; bias=bi1; fea=fe1; shadow=sh1; n=n1;
                wid = ((b-nb0)*256 + threadIdx.x) >> 6; }
  if (wid >= n) return;
  int v = wid;
  float edv = ed[v];
  float self_e = leakyr(es[v] + edv);
  int beg = rowptr[v], end = rowptr[v+1];
  // softmax pass: lane-strided online max+sum
  float m = -3.4e38f, s = 0.f;
  for (int i = beg + lane; i < end; i += 64){
    float e = leakyr(es[epk[i].x] + edv);
    if (e > m){ s = s*expf(m - e) + 1.0f; m = e; }
    else s += expf(e - m);
  }
  #pragma unroll
  for (int off = 32; off; off >>= 1){
    float m2 = __shfl_xor(m, off), s2 = __shfl_xor(s, off);
    float mn_ = fmaxf(m, m2);
    s = s*expf(m - mn_) + s2*expf(m2 - mn_);
    m = mn_;
  }
  {
    float mn_ = fmaxf(m, self_e);
    s = s*expf(m - mn_) + expf(self_e - mn_);
    m = mn_;
  }
  float inv_s = 1.0f / s;
  // feature pass: 2 edges/wave, 4 channels/lane
  int half = lane >> 5;
  int hl   = lane & 31;
  uint2 hv = *(const uint2*)(H + (size_t)v*EMB + hl*4);
  float aw = expf(self_e - m)*inv_s;
  float a0, a1, a2, a3;
  if (half == 0){
    a0 = aw*bfl(hv.x); a1 = aw*bfh(hv.x); a2 = aw*bfl(hv.y); a3 = aw*bfh(hv.y);
  } else { a0 = a1 = a2 = a3 = 0.f; }
  int i = beg + half;
  for (; i + 2 < end; i += 4){
    int rA = epk[i].x, rB = epk[i+2].x;
    float aA = expf(leakyr(es[rA] + edv) - m)*inv_s;
    float aB = expf(leakyr(es[rB] + edv) - m)*inv_s;
    uint2 hA = *(const uint2*)(H + (size_t)rA*EMB + hl*4);
    uint2 hB = *(const uint2*)(H + (size_t)rB*EMB + hl*4);
    a0 += aA*bfl(hA.x) + aB*bfl(hB.x);
    a1 += aA*bfh(hA.x) + aB*bfh(hB.x);
    a2 += aA*bfl(hA.y) + aB*bfl(hB.y);
    a3 += aA*bfh(hA.y) + aB*bfh(hB.y);
  }
  if (i < end){
    int r = epk[i].x;
    float a = expf(leakyr(es[r] + edv) - m)*inv_s;
    uint2 h = *(const uint2*)(H + (size_t)r*EMB + hl*4);
    a0 += a*bfl(h.x); a1 += a*bfh(h.x); a2 += a*bfl(h.y); a3 += a*bfh(h.y);
  }
  a0 += __shfl_xor(a0, 32); a1 += __shfl_xor(a1, 32);
  a2 += __shfl_xor(a2, 32); a3 += __shfl_xor(a3, 32);
  if (half == 0){
    float4 b4 = *(const float4*)(bias + hl*4);
    float o0 = eluf(a0 + b4.x), o1 = eluf(a1 + b4.y);
    float o2 = eluf(a2 + b4.z), o3 = eluf(a3 + b4.w);
    float* fp = fea + (size_t)v*EMB + hl*4;
    float4 f = *(float4*)fp;
    float f0 = (f.x + o0)/3.0f, f1 = (f.y + o1)/3.0f;
    float f2 = (f.z + o2)/3.0f, f3 = (f.w + o3)/3.0f;
    *(float4*)fp = make_float4(f0, f1, f2, f3);
    uint2 sh;
    sh.x = bf16u(f0) | (bf16u(f1) << 16);
    sh.y = bf16u(f2) | (bf16u(f3) << 16);
    *(uint2*)(shadow + (size_t)v*64 + hl*2) = sh;
  }
}

// ================= score GEMM v5: dbuf, 16 j-tiles/block; pass0 self-reduces min/max =================
__device__ __forceinline__ void stage128(const uint8_t* G, uint8_t* L, int w, int lane){
  #pragma unroll
  for (int c = 0; c < 8; ++c){
    int linear = w*8192 + c*1024 + lane*16;
    int row = linear >> 8, col = linear & 255;
    const void* src = G + row*256 + (col ^ ((row & 7) << 4));
    __builtin_amdgcn_global_load_lds(
        (const __attribute__((address_space(1))) void*)src,
        (__attribute__((address_space(3))) void*)(L + w*8192 + c*1024),
        16, 0, 0);
  }
}

#define NT 16
template<int STORE>
__global__ __launch_bounds__(256) void k_score5(const ushort* __restrict__ Abf,
                                                const ushort* __restrict__ Bbf,
                                                float* __restrict__ S,
                                                float* __restrict__ mmpart){
  __shared__ __align__(16) uint8_t L0[32768];
  __shared__ __align__(16) uint8_t L1[32768];
  __shared__ float red[16];
  __shared__ unsigned sdone;
  const int t = threadIdx.x;
  const int lane = t & 63;
  const int w = t >> 6;
  const int wr = w >> 1, wc = w & 1;
  const int lr = lane & 15, lk = lane >> 4;
  const int i0b = blockIdx.y * 128;
  const int jbase = blockIdx.x * NT;

  stage128((const uint8_t*)(Abf + (size_t)i0b*EMB), L0, w, lane);
  stage128((const uint8_t*)(Bbf + (size_t)jbase*128*EMB), L1, w, lane);
  __syncthreads();

  short8 af[4][4];
  #pragma unroll
  for (int at = 0; at < 4; ++at){
    int ra = wr*64 + at*16 + lr;
    #pragma unroll
    for (int k0 = 0; k0 < 4; ++k0){
      int kb = k0*64 + lk*16;
      af[at][k0] = *(const short8*)&L0[ra*256 + (kb ^ ((ra & 7) << 4))];
    }
  }
  __syncthreads();
  stage128((const uint8_t*)(Bbf + (size_t)(jbase+1)*128*EMB), L0, w, lane);

  float mn = 0.f, sc = 0.f;
  if (STORE){
    mn = mmpart[0];
    float mx = mmpart[1];
    sc = (mx > mn) ? 1.0f/(mx - mn) : 0.0f;
  }
  float lmin = 3.4e38f, lmax = -3.4e38f;

  for (int jt = 0; jt < NT; ++jt){
    uint8_t* curB = (jt & 1) ? L0 : L1;
    f32x4 acc[4][4];
    #pragma unroll
    for (int a = 0; a < 4; ++a)
      #pragma unroll
      for (int b = 0; b < 4; ++b) acc[a][b] = (f32x4){0.f,0.f,0.f,0.f};

    #pragma unroll
    for (int k0 = 0; k0 < 4; ++k0){
      int kb = k0*64 + lk*16;
      short8 bfr[4];
      #pragma unroll
      for (int ct = 0; ct < 4; ++ct){
        int rb = wc*64 + ct*16 + lr;
        bfr[ct] = *(const short8*)&curB[rb*256 + (kb ^ ((rb & 7) << 4))];
      }
      #pragma unroll
      for (int at = 0; at < 4; ++at)
        #pragma unroll
        for (int ct = 0; ct < 4; ++ct)
          acc[at][ct] = __builtin_amdgcn_mfma_f32_16x16x32_bf16(af[at][k0], bfr[ct], acc[at][ct], 0, 0, 0);
    }

    int j0 = (jbase + jt)*128;
    if (STORE){
      #pragma unroll
      for (int at = 0; at < 4; ++at){
        #pragma unroll
        for (int ct = 0; ct < 4; ++ct){
          int colj = j0 + wc*64 + ct*16 + lr;
          int row0 = i0b + wr*64 + at*16 + lk*4;
          #pragma unroll
          for (int q = 0; q < 4; ++q){
            float vv = fminf(fmaxf((acc[at][ct][q] - mn)*sc, 0.f), 1.f);
            S[(size_t)(row0+q)*DIS_NN + colj] = vv;
          }
        }
      }
    } else {
      #pragma unroll
      for (int at = 0; at < 4; ++at)
        #pragma unroll
        for (int ct = 0; ct < 4; ++ct)
          #pragma unroll
          for (int q = 0; q < 4; ++q){
            float vv = acc[at][ct][q];
            lmin = fminf(lmin, vv); lmax = fmaxf(lmax, vv);
          }
    }
    __syncthreads();
    if (jt + 2 < NT)
      stage128((const uint8_t*)(Bbf + (size_t)(jbase+jt+2)*128*EMB), curB, w, lane);
  }

  if (!STORE){
    #pragma unroll
    for (int off = 32; off; off >>= 1){
      lmin = fminf(lmin, __shfl_xor(lmin, off));
      lmax = fmaxf(lmax, __shfl_xor(lmax, off));
    }
    if (lane == 0){ red[w*2] = lmin; red[w*2+1] = lmax; }
    __syncthreads();
    unsigned* ctr = (unsigned*)(mmpart + 1088);
    if (t == 0){
      float a = fminf(fminf(red[0], red[2]), fminf(red[4], red[6]));
      float b = fmaxf(fmaxf(red[1], red[3]), fmaxf(red[5], red[7]));
      int bid = blockIdx.y * 4 + blockIdx.x;      // 512 blocks
      mmpart[2 + bid*2]     = a;
      mmpart[2 + bid*2 + 1] = b;
      __threadfence();
      sdone = atomicAdd(ctr, 1u);
    }
    __syncthreads();
    if (sdone == 511u){                            // last block reduces all partials
      __threadfence();
      float mnv = fminf(mmpart[2 + 2*t], mmpart[2 + 2*(t+256)]);
      float mxv = fmaxf(mmpart[3 + 2*t], mmpart[3 + 2*(t+256)]);
      #pragma unroll
      for (int off = 32; off; off >>= 1){
        mnv = fminf(mnv, __shfl_xor(mnv, off));
        mxv = fmaxf(mxv, __shfl_xor(mxv, off));
      }
      if (lane == 0){ red[w*2] = mnv; red[w*2+1] = mxv; }
      __syncthreads();
      if (t == 0){
        float a = fminf(fminf(red[0], red[2]), fminf(red[4], red[6]));
        float b = fmaxf(fmaxf(red[1], red[3]), fmaxf(red[5], red[7]));
        mmpart[0] = a; mmpart[1] = b;
      }
    }
  }
}

// ================= host =================
extern "C" void kernel_launch(void* const* d_in, const int* in_sizes, int n_in,
                              void* d_out, int out_size, void* d_ws, size_t ws_size,
                              hipStream_t stream){
  (void)in_sizes; (void)n_in; (void)out_size; (void)ws_size;
  const float* mm_x0  = (const float*)d_in[0];
  const float* dd_x0  = (const float*)d_in[1];
  const float* w1_mm  = (const float*)d_in[2];
  const float* b1_mm  = (const float*)d_in[3];
  const float* w2_mm  = (const float*)d_in[4];
  const float* b2_mm  = (const float*)d_in[5];
  const float* w3_mm  = (const float*)d_in[6];
  const float* asrc_mm= (const float*)d_in[7];
  const float* adst_mm= (const float*)d_in[8];
  const float* b3_mm  = (const float*)d_in[9];
  const float* w1_dd  = (const float*)d_in[10];
  const float* b1_dd  = (const float*)d_in[11];
  const float* w2_dd  = (const float*)d_in[12];
  const float* b2_dd  = (const float*)d_in[13];
  const float* w3_dd  = (const float*)d_in[14];
  const float* asrc_dd= (const float*)d_in[15];
  const float* adst_dd= (const float*)d_in[16];
  const float* b3_dd  = (const float*)d_in[17];
  const float* mm_ew  = (const float*)d_in[18];
  const float* dd_ew  = (const float*)d_in[19];
  const int* mm_edges = (const int*)d_in[20];
  const int* dd_edges = (const int*)d_in[21];

  float* S = (float*)d_out;
  float* p = S;
  float* A0m = p;  p += (size_t)MI_NN*EMB;
  float* A1m = p;  p += (size_t)MI_NN*EMB;
  float* A0d = p;  p += (size_t)DIS_NN*EMB;
  float* A1d = p;  p += (size_t)DIS_NN*EMB;
  ushort* Hbm = (ushort*)p; p += (size_t)MI_NN*EMB/2;
  ushort* Hbd = (ushort*)p; p += (size_t)DIS_NN*EMB/2;
  float* DEG1m = p; p += MI_NN;
  float* DEG2m = p; p += MI_NN;
  float* ESm   = p; p += MI_NN;
  float* EDm   = p; p += MI_NN;
  float* DEG1d = p; p += DIS_NN;
  float* DEG2d = p; p += DIS_NN;
  float* ESd   = p; p += DIS_NN;
  float* EDd   = p; p += DIS_NN;
  int* CNTm  = (int*)p; p += MI_NN;
  int* CNTd  = (int*)p; p += DIS_NN;
  int* FILLm = (int*)p; p += MI_NN;
  int* FILLd = (int*)p; p += DIS_NN;
  int* RPm   = (int*)p; p += MI_NN + 64;
  int* RPd   = (int*)p; p += DIS_NN + 64;
  int2* EPKm = (int2*)p; p += (size_t)EMM*2;
  int2* EPKd = (int2*)p; p += (size_t)EDD*2;
  float* FEA_MI  = S + (size_t)MI_NN * DIS_NN;
  float* FEA_DIS = FEA_MI + (size_t)MI_NN*EMB;

  float* MM = (float*)d_ws;                       // [0,1] mn/mx; [2..1026) partials; [1088] counter
  ushort* Abf = (ushort*)((char*)d_ws + 16384);
  ushort* Bbf = Abf + (size_t)MI_NN * EMB;

  const int* erow_m = mm_edges;
  const int* ecol_m = mm_edges + EMM;
  const int* erow_d = dd_edges;
  const int* ecol_d = dd_edges + EDD;

  // ---- CSR build ----
  hipMemsetAsync(CNTm, 0, (size_t)2*(MI_NN + DIS_NN)*sizeof(int), stream);
  k_count2g<<<EMM/256 + EDD/256, 256, 0, stream>>>(ecol_m, CNTm, EMM, EMM/256,
                                                   ecol_d, CNTd, EDD,
                                                   (unsigned*)(MM + 1088));
  k_scan2g<<<2, 1024, 0, stream>>>(CNTm, RPm, MI_NN, EMM, CNTd, RPd, DIS_NN, EDD);
  k_fill2g<<<EMM/256 + EDD/256, 256, 0, stream>>>(erow_m, ecol_m, mm_ew, RPm, FILLm, EPKm,
                                                  EMM, EMM/256,
                                                  erow_d, ecol_d, dd_ew, RPd, FILLd, EPKd,
                                                  EDD);
  const int GB = MI_NN/32 + DIS_NN/32;
  const int AB = MI_NN/4 + DIS_NN/4;
  // ---- layer 1: GCN with edge weights ----
  k_gemm2g<0><<<GB, 256, 0, stream>>>(mm_x0, w1_mm, Hbm, MI_NN/32, dd_x0, w1_dd, Hbd,
                                      nullptr, nullptr, nullptr, nullptr,
                                      nullptr, nullptr, nullptr, nullptr);
  k_deg2g<<<AB, 256, 0, stream>>>(RPm, EPKm, DEG1m, DEG2m, MI_NN, MI_NN/4,
                                  RPd, EPKd, DEG1d, DEG2d, DIS_NN);
  k_agg2g<<<AB, 256, 0, stream>>>(Hbm, DEG1m, RPm, EPKm, b1_mm, A0m, FEA_MI, MI_NN, MI_NN/4,
                                  Hbd, DEG1d, RPd, EPKd, b1_dd, A0d, FEA_DIS, DIS_NN, 1, 0);
  // ---- layer 2: GCN, unit weights ----
  k_gemm2g<0><<<GB, 256, 0, stream>>>(A0m, w2_mm, Hbm, MI_NN/32, A0d, w2_dd, Hbd,
                                      nullptr, nullptr, nullptr, nullptr,
                                      nullptr, nullptr, nullptr, nullptr);
  k_agg2g<<<AB, 256, 0, stream>>>(Hbm, DEG2m, RPm, EPKm, b2_mm, A1m, FEA_MI, MI_NN, MI_NN/4,
                                  Hbd, DEG2d, RPd, EPKd, b2_dd, A1d, FEA_DIS, DIS_NN, 0, 1);
  // ---- layer 3: GAT (srcdst fused into gemm) ----
  k_gemm2g<1><<<GB, 256, 0, stream>>>(A1m, w3_mm, Hbm, MI_NN/32, A1d, w3_dd, Hbd,
                                      asrc_mm, adst_mm, ESm, EDm,
                                      asrc_dd, adst_dd, ESd, EDd);
  k_gat2g<<<AB, 256, 0, stream>>>(Hbm, ESm, EDm, RPm, EPKm, b3_mm, FEA_MI, (unsigned*)Abf, MI_NN, MI_NN/4,
                                  Hbd, ESd, EDd, RPd, EPKd, b3_dd, FEA_DIS, (unsigned*)Bbf, DIS_NN);
  // ---- score (pass0 reduces min/max internally via last-block) ----
  k_score5<0><<<dim3(DIS_NN/(128*NT), MI_NN/128), 256, 0, stream>>>(Abf, Bbf, nullptr, MM);
  k_score5<1><<<dim3(DIS_NN/(128*NT), MI_NN/128), 256, 0, stream>>>(Abf, Bbf, S, MM);
}

// Round 10
// 396.522 us; speedup vs baseline: 1.1029x; 1.1029x over previous
//
#include <hip/hip_runtime.h>
#include <cstdint>
#include <cstddef>

#define MI_NN 16384
#define DIS_NN 8192
#define EMB 128
#define EMM (MI_NN*32)
#define EDD (DIS_NN*32)

typedef __attribute__((ext_vector_type(8))) short short8;
typedef __attribute__((ext_vector_type(4))) float f32x4;

__device__ __forceinline__ float leakyr(float x){ return x > 0.f ? x : 0.2f*x; }
__device__ __forceinline__ float eluf(float x){ return x > 0.f ? x : expm1f(x); }

__device__ __forceinline__ unsigned bf16u(float x){
  unsigned u = __float_as_uint(x);
  return (u + 0x7FFFu + ((u >> 16) & 1u)) >> 16;   // RNE
}
__device__ __forceinline__ float bfl(unsigned p){ return __uint_as_float(p << 16); }
__device__ __forceinline__ float bfh(unsigned p){ return __uint_as_float(p & 0xFFFF0000u); }

// ================= prep: pack x0 -> bf16, W -> W^T bf16 =================
__global__ __launch_bounds__(256) void k_prep(const float* __restrict__ x0m, const float* __restrict__ x0d,
    const float* __restrict__ w1m, const float* __restrict__ w2m, const float* __restrict__ w3m,
    const float* __restrict__ w1d, const float* __restrict__ w2d, const float* __restrict__ w3d,
    ushort* __restrict__ Xm, ushort* __restrict__ Xd, ushort* __restrict__ Wt){
  int b = blockIdx.x, t = threadIdx.x;
  if (b < 1536){
    const float* src; ushort* dst; int i;
    if (b < 1024){ src = x0m; dst = Xm; i = b*256 + t; }
    else         { src = x0d; dst = Xd; i = (b-1024)*256 + t; }
    const float4* X4 = (const float4*)src;
    float4 a = X4[(size_t)i*2], c = X4[(size_t)i*2+1];
    union { ushort u[8]; uint4 v; } r;
    r.u[0]=(ushort)bf16u(a.x); r.u[1]=(ushort)bf16u(a.y);
    r.u[2]=(ushort)bf16u(a.z); r.u[3]=(ushort)bf16u(a.w);
    r.u[4]=(ushort)bf16u(c.x); r.u[5]=(ushort)bf16u(c.y);
    r.u[6]=(ushort)bf16u(c.z); r.u[7]=(ushort)bf16u(c.w);
    ((uint4*)dst)[i] = r.v;
  } else {
    int m = b - 1536;                      // 0..5
    const float* W = (m==0)?w1m:(m==1)?w2m:(m==2)?w3m:(m==3)?w1d:(m==4)?w2d:w3d;
    ushort* dst = Wt + m*16384;
    for (int it = 0; it < 64; ++it){
      int o = it*256 + t;
      int j = o >> 7, k = o & 127;
      dst[o] = (ushort)bf16u(W[k*128 + j]);   // Wt[j][k] = W[k][j]
    }
  }
}

// ================= CSR build (merged MM+DD) =================
__global__ __launch_bounds__(256) void k_count2g(const int* __restrict__ c0, int* __restrict__ n0c,
                                                 int E0, int nb0,
                                                 const int* __restrict__ c1, int* __restrict__ n1c,
                                                 int E1, unsigned* __restrict__ ctr){
  if (blockIdx.x == 0 && threadIdx.x == 0) ctr[0] = 0u;
  int b = blockIdx.x;
  const int* col; int* cnt; int E; int t;
  if (b < nb0){ col = c0; cnt = n0c; E = E0; t = b*256 + threadIdx.x; }
  else        { col = c1; cnt = n1c; E = E1; t = (b - nb0)*256 + threadIdx.x; }
  if (t < E) atomicAdd(&cnt[col[t]], 1);
}

__global__ __launch_bounds__(1024) void k_scan2g(const int* __restrict__ cnt0, int* __restrict__ rp0,
                                                 int n0, int E0,
                                                 const int* __restrict__ cnt1, int* __restrict__ rp1,
                                                 int n1, int E1){
  const int* cnt = blockIdx.x ? cnt1 : cnt0;
  int* rowptr    = blockIdx.x ? rp1  : rp0;
  int n          = blockIdx.x ? n1   : n0;
  int E          = blockIdx.x ? E1   : E0;
  __shared__ int lds[1024];
  int t = threadIdx.x;
  int chunk = n >> 10;
  int base = t*chunk;
  int s = 0;
  for (int i = 0; i < chunk; ++i) s += cnt[base+i];
  lds[t] = s; __syncthreads();
  for (int off = 1; off < 1024; off <<= 1){
    int v = (t >= off) ? lds[t-off] : 0;
    __syncthreads();
    lds[t] += v;
    __syncthreads();
  }
  int run = lds[t] - s;
  for (int i = 0; i < chunk; ++i){ rowptr[base+i] = run; run += cnt[base+i]; }
  if (t == 0) rowptr[n] = E;
}

__global__ __launch_bounds__(256) void k_fill2g(
    const int* __restrict__ r0a, const int* __restrict__ c0a, const float* __restrict__ w0a,
    const int* __restrict__ rp0, int* __restrict__ f0, int2* __restrict__ e0,
    int E0, int nb0,
    const int* __restrict__ r1a, const int* __restrict__ c1a, const float* __restrict__ w1a,
    const int* __restrict__ rp1, int* __restrict__ f1, int2* __restrict__ e1,
    int E1){
  int b = blockIdx.x;
  const int *row, *col; const float* ew; const int* rowptr;
  int* fill; int2* epk; int E, t;
  if (b < nb0){ row=r0a; col=c0a; ew=w0a; rowptr=rp0; fill=f0; epk=e0; E=E0; t=b*256+threadIdx.x; }
  else        { row=r1a; col=c1a; ew=w1a; rowptr=rp1; fill=f1; epk=e1; E=E1; t=(b-nb0)*256+threadIdx.x; }
  if (t < E){
    int c = col[t];
    int p = rowptr[c] + atomicAdd(&fill[c], 1);
    epk[p] = make_int2(row[t], __float_as_int(ew[t]));
  }
}

// ================= staging helper (pre-swizzled source, linear LDS dest) =================
__device__ __forceinline__ void stage128(const uint8_t* G, uint8_t* L, int w, int lane){
  #pragma unroll
  for (int c = 0; c < 8; ++c){
    int linear = w*8192 + c*1024 + lane*16;
    int row = linear >> 8, col = linear & 255;
    const void* src = G + row*256 + (col ^ ((row & 7) << 4));
    __builtin_amdgcn_global_load_lds(
        (const __attribute__((address_space(1))) void*)src,
        (__attribute__((address_space(3))) void*)(L + w*8192 + c*1024),
        16, 0, 0);
  }
}

// ================= layer GEMM via MFMA: H = X(bf16) @ W (Wt = W^T bf16) =================
template<int FUSE>
__global__ __launch_bounds__(256) void k_gemm_mfma(
    const ushort* __restrict__ X0, const ushort* __restrict__ Wt0, ushort* __restrict__ H0, int nb0,
    const ushort* __restrict__ X1, const ushort* __restrict__ Wt1, ushort* __restrict__ H1,
    const float* __restrict__ as0, const float* __restrict__ ad0,
    float* __restrict__ es0, float* __restrict__ ed0,
    const float* __restrict__ as1, const float* __restrict__ ad1,
    float* __restrict__ es1, float* __restrict__ ed1){
  __shared__ __align__(16) uint8_t Xl[32768];
  __shared__ __align__(16) uint8_t Wl[32768];
  __shared__ float esp[2][128], edp[2][128];
  int b = blockIdx.x;
  const ushort *X, *Wt; ushort* H; const float *asr, *ads; float *es, *ed; int rb;
  if (b < nb0){ X=X0; Wt=Wt0; H=H0; asr=as0; ads=ad0; es=es0; ed=ed0; rb = b; }
  else        { X=X1; Wt=Wt1; H=H1; asr=as1; ads=ad1; es=es1; ed=ed1; rb = b - nb0; }
  const int t = threadIdx.x;
  const int lane = t & 63, w = t >> 6;
  const int wr = w >> 1, wc = w & 1;
  const int lr = lane & 15, lk = lane >> 4;
  const int i0 = rb*128;

  stage128((const uint8_t*)(X + (size_t)i0*EMB), Xl, w, lane);
  stage128((const uint8_t*)Wt, Wl, w, lane);
  __syncthreads();

  short8 af[4][4];
  #pragma unroll
  for (int at = 0; at < 4; ++at){
    int ra = wr*64 + at*16 + lr;
    #pragma unroll
    for (int k0 = 0; k0 < 4; ++k0){
      int kb = k0*64 + lk*16;
      af[at][k0] = *(const short8*)&Xl[ra*256 + (kb ^ ((ra & 7) << 4))];
    }
  }
  f32x4 acc[4][4];
  #pragma unroll
  for (int a = 0; a < 4; ++a)
    #pragma unroll
    for (int c = 0; c < 4; ++c) acc[a][c] = (f32x4){0.f,0.f,0.f,0.f};
  #pragma unroll
  for (int k0 = 0; k0 < 4; ++k0){
    int kb = k0*64 + lk*16;
    short8 bfr[4];
    #pragma unroll
    for (int ct = 0; ct < 4; ++ct){
      int rbw = wc*64 + ct*16 + lr;
      bfr[ct] = *(const short8*)&Wl[rbw*256 + (kb ^ ((rbw & 7) << 4))];
    }
    #pragma unroll
    for (int at = 0; at < 4; ++at)
      #pragma unroll
      for (int ct = 0; ct < 4; ++ct)
        acc[at][ct] = __builtin_amdgcn_mfma_f32_16x16x32_bf16(af[at][k0], bfr[ct], acc[at][ct], 0, 0, 0);
  }
  // H store (bf16)
  #pragma unroll
  for (int at = 0; at < 4; ++at){
    #pragma unroll
    for (int ct = 0; ct < 4; ++ct){
      int colj = wc*64 + ct*16 + lr;
      int row0 = i0 + wr*64 + at*16 + lk*4;
      #pragma unroll
      for (int q = 0; q < 4; ++q)
        H[(size_t)(row0+q)*EMB + colj] = (ushort)bf16u(acc[at][ct][q]);
    }
  }
  if (FUSE){
    float sv[4], dv4[4];
    #pragma unroll
    for (int ct = 0; ct < 4; ++ct){
      sv[ct]  = asr[wc*64 + ct*16 + lr];
      dv4[ct] = ads[wc*64 + ct*16 + lr];
    }
    #pragma unroll
    for (int at = 0; at < 4; ++at){
      #pragma unroll
      for (int q = 0; q < 4; ++q){
        float ps = acc[at][0][q]*sv[0] + acc[at][1][q]*sv[1] + acc[at][2][q]*sv[2] + acc[at][3][q]*sv[3];
        float pd = acc[at][0][q]*dv4[0] + acc[at][1][q]*dv4[1] + acc[at][2][q]*dv4[2] + acc[at][3][q]*dv4[3];
        #pragma unroll
        for (int off = 8; off; off >>= 1){
          ps += __shfl_xor(ps, off);
          pd += __shfl_xor(pd, off);
        }
        if (lr == 0){
          int rl = wr*64 + at*16 + lk*4 + q;
          esp[wc][rl] = ps; edp[wc][rl] = pd;
        }
      }
    }
    __syncthreads();
    if (t < 128) es[i0 + t] = esp[0][t] + esp[1][t];
    else { int r = t - 128; ed[i0 + r] = edp[0][r] + edp[1][r]; }
  }
}

// ================= degree: DEG1 + DEG2, both graphs =================
__global__ __launch_bounds__(256) void k_deg2g(
    const int* __restrict__ rp0, const int2* __restrict__ ep0,
    float* __restrict__ d10, float* __restrict__ d20, int n0, int nb0,
    const int* __restrict__ rp1, const int2* __restrict__ ep1,
    float* __restrict__ d11, float* __restrict__ d21, int n1){
  int b = blockIdx.x;
  const int* rowptr; const int2* epk; float *d1, *d2; int n, wid;
  int lane = threadIdx.x & 63;
  if (b < nb0){ rowptr=rp0; epk=ep0; d1=d10; d2=d20; n=n0; wid = (b*256 + threadIdx.x) >> 6; }
  else        { rowptr=rp1; epk=ep1; d1=d11; d2=d21; n=n1; wid = ((b-nb0)*256 + threadIdx.x) >> 6; }
  if (wid >= n) return;
  int beg = rowptr[wid], end = rowptr[wid+1];
  float s = 0.f;
  for (int i = beg + lane; i < end; i += 64) s += __int_as_float(epk[i].y);
  #pragma unroll
  for (int off = 32; off; off >>= 1) s += __shfl_xor(s, off);
  if (lane == 0){
    d1[wid] = rsqrtf(1.0f + s);
    d2[wid] = rsqrtf(1.0f + (float)(end - beg));
  }
}

// ================= GCN aggregation: 8 gathers in flight/wave, bf16 xnext =================
__global__ __launch_bounds__(256) void k_agg2g(
    const ushort* __restrict__ H0, const float* __restrict__ di0, const int* __restrict__ rp0,
    const int2* __restrict__ ep0, const float* __restrict__ bi0,
    ushort* __restrict__ xn0, float* __restrict__ fe0, int n0, int nb0,
    const ushort* __restrict__ H1, const float* __restrict__ di1, const int* __restrict__ rp1,
    const int2* __restrict__ ep1, const float* __restrict__ bi1,
    ushort* __restrict__ xn1, float* __restrict__ fe1, int n1,
    int useew, int femode){
  int b = blockIdx.x;
  const ushort* H; const float* dinv; const int* rowptr; const int2* epk;
  const float* bias; ushort* xnext; float* fea; int n, wid;
  int lane = threadIdx.x & 63;
  if (b < nb0){ H=H0; dinv=di0; rowptr=rp0; epk=ep0; bias=bi0; xnext=xn0; fea=fe0; n=n0;
                wid = (b*256 + threadIdx.x) >> 6; }
  else        { H=H1; dinv=di1; rowptr=rp1; epk=ep1; bias=bi1; xnext=xn1; fea=fe1; n=n1;
                wid = ((b-nb0)*256 + threadIdx.x) >> 6; }
  if (wid >= n) return;
  int v = wid;
  int half = lane >> 5;
  int hl   = lane & 31;
  float dv = dinv[v];
  uint2 hv = *(const uint2*)(H + (size_t)v*EMB + hl*4);
  float a0, a1, a2, a3;
  if (half == 0){
    a0 = dv*bfl(hv.x); a1 = dv*bfh(hv.x); a2 = dv*bfl(hv.y); a3 = dv*bfh(hv.y);
  } else { a0 = a1 = a2 = a3 = 0.f; }
  int beg = rowptr[v], end = rowptr[v+1];
  int i = beg + half;
  for (; i + 6 < end; i += 8){
    int2 eA = epk[i], eB = epk[i+2], eC = epk[i+4], eD = epk[i+6];
    float nA = dinv[eA.x], nB = dinv[eB.x], nC = dinv[eC.x], nD = dinv[eD.x];
    if (useew){ nA *= __int_as_float(eA.y); nB *= __int_as_float(eB.y);
                nC *= __int_as_float(eC.y); nD *= __int_as_float(eD.y); }
    uint2 hA = *(const uint2*)(H + (size_t)eA.x*EMB + hl*4);
    uint2 hB = *(const uint2*)(H + (size_t)eB.x*EMB + hl*4);
    uint2 hC = *(const uint2*)(H + (size_t)eC.x*EMB + hl*4);
    uint2 hD = *(const uint2*)(H + (size_t)eD.x*EMB + hl*4);
    a0 += nA*bfl(hA.x) + nB*bfl(hB.x) + nC*bfl(hC.x) + nD*bfl(hD.x);
    a1 += nA*bfh(hA.x) + nB*bfh(hB.x) + nC*bfh(hC.x) + nD*bfh(hD.x);
    a2 += nA*bfl(hA.y) + nB*bfl(hB.y) + nC*bfl(hC.y) + nD*bfl(hD.y);
    a3 += nA*bfh(hA.y) + nB*bfh(hB.y) + nC*bfh(hC.y) + nD*bfh(hD.y);
  }
  for (; i < end; i += 2){
    int2 e = epk[i];
    float nm = dinv[e.x];
    if (useew) nm *= __int_as_float(e.y);
    uint2 h = *(const uint2*)(H + (size_t)e.x*EMB + hl*4);
    a0 += nm*bfl(h.x); a1 += nm*bfh(h.x); a2 += nm*bfl(h.y); a3 += nm*bfh(h.y);
  }
  a0 += __shfl_xor(a0, 32); a1 += __shfl_xor(a1, 32);
  a2 += __shfl_xor(a2, 32); a3 += __shfl_xor(a3, 32);
  if (half == 0){
    float4 b4 = *(const float4*)(bias + hl*4);
    float o0 = eluf(dv*a0 + b4.x), o1 = eluf(dv*a1 + b4.y);
    float o2 = eluf(dv*a2 + b4.z), o3 = eluf(dv*a3 + b4.w);
    uint2 xn2;
    xn2.x = bf16u(o0) | (bf16u(o1) << 16);
    xn2.y = bf16u(o2) | (bf16u(o3) << 16);
    *(uint2*)(xnext + (size_t)v*EMB + hl*4) = xn2;
    float* fp = fea + (size_t)v*EMB + hl*4;
    if (femode == 0){
      *(float4*)fp = make_float4(o0, o1, o2, o3);
    } else {
      float4 f = *(float4*)fp;
      *(float4*)fp = make_float4(f.x + o0, f.y + o1, f.z + o2, f.w + o3);
    }
  }
}

// ================= GAT aggregation + bf16 shadow, deeper ILP =================
__global__ __launch_bounds__(256) void k_gat2g(
    const ushort* __restrict__ H0, const float* __restrict__ es0, const float* __restrict__ ed0,
    const int* __restrict__ rp0, const int2* __restrict__ ep0, const float* __restrict__ bi0,
    float* __restrict__ fe0, unsigned* __restrict__ sh0, int n0, int nb0,
    const ushort* __restrict__ H1, const float* __restrict__ es1, const float* __restrict__ ed1,
    const int* __restrict__ rp1, const int2* __restrict__ ep1, const float* __restrict__ bi1,
    float* __restrict__ fe1, unsigned* __restrict__ sh1, int n1){
  int b = blockIdx.x;
  const ushort* H; const float *es, *ed; const int* rowptr; const int2* epk; const float* bias;
  float* fea; unsigned* shadow; int n, wid;
  int lane = threadIdx.x & 63;
  if (b < nb0){ H=H0; es=es0; ed=ed0; rowptr=rp0; epk=ep0; bias=bi0; fea=fe0; shadow=sh0; n=n0;
                wid = (b*256 + threadIdx.x) >> 6; }
  else        { H=H1; es=es1; ed=ed1; rowptr=rp1; epk=ep1; bias=bi1; fea=fe1; shadow=sh1; n=n1;
                wid = ((b-nb0)*256 + threadIdx.x) >> 6; }
  if (wid >= n) return;
  int v = wid;
  float edv = ed[v];
  float self_e = leakyr(es[v] + edv);
  int beg = rowptr[v], end = rowptr[v+1];
  float m = -3.4e38f, s = 0.f;
  for (int i = beg + lane; i < end; i += 64){
    float e = leakyr(es[epk[i].x] + edv);
    if (e > m){ s = s*expf(m - e) + 1.0f; m = e; }
    else s += expf(e - m);
  }
  #pragma unroll
  for (int off = 32; off; off >>= 1){
    float m2 = __shfl_xor(m, off), s2 = __shfl_xor(s, off);
    float mn_ = fmaxf(m, m2);
    s = s*expf(m - mn_) + s2*expf(m2 - mn_);
    m = mn_;
  }
  {
    float mn_ = fmaxf(m, self_e);
    s = s*expf(m - mn_) + expf(self_e - mn_);
    m = mn_;
  }
  float inv_s = 1.0f / s;
  int half = lane >> 5;
  int hl   = lane & 31;
  uint2 hv = *(const uint2*)(H + (size_t)v*EMB + hl*4);
  float aw = expf(self_e - m)*inv_s;
  float a0, a1, a2, a3;
  if (half == 0){
    a0 = aw*bfl(hv.x); a1 = aw*bfh(hv.x); a2 = aw*bfl(hv.y); a3 = aw*bfh(hv.y);
  } else { a0 = a1 = a2 = a3 = 0.f; }
  int i = beg + half;
  for (; i + 6 < end; i += 8){
    int rA = epk[i].x, rB = epk[i+2].x, rC = epk[i+4].x, rD = epk[i+6].x;
    float aA = expf(leakyr(es[rA] + edv) - m)*inv_s;
    float aB = expf(leakyr(es[rB] + edv) - m)*inv_s;
    float aC = expf(leakyr(es[rC] + edv) - m)*inv_s;
    float aD = expf(leakyr(es[rD] + edv) - m)*inv_s;
    uint2 hA = *(const uint2*)(H + (size_t)rA*EMB + hl*4);
    uint2 hB = *(const uint2*)(H + (size_t)rB*EMB + hl*4);
    uint2 hC = *(const uint2*)(H + (size_t)rC*EMB + hl*4);
    uint2 hD = *(const uint2*)(H + (size_t)rD*EMB + hl*4);
    a0 += aA*bfl(hA.x) + aB*bfl(hB.x) + aC*bfl(hC.x) + aD*bfl(hD.x);
    a1 += aA*bfh(hA.x) + aB*bfh(hB.x) + aC*bfh(hC.x) + aD*bfh(hD.x);
    a2 += aA*bfl(hA.y) + aB*bfl(hB.y) + aC*bfl(hC.y) + aD*bfl(hD.y);
    a3 += aA*bfh(hA.y) + aB*bfh(hB.y) + aC*bfh(hC.y) + aD*bfh(hD.y);
  }
  for (; i < end; i += 2){
    int r = epk[i].x;
    float a = expf(leakyr(es[r] + edv) - m)*inv_s;
    uint2 h = *(const uint2*)(H + (size_t)r*EMB + hl*4);
    a0 += a*bfl(h.x); a1 += a*bfh(h.x); a2 += a*bfl(h.y); a3 += a*bfh(h.y);
  }
  a0 += __shfl_xor(a0, 32); a1 += __shfl_xor(a1, 32);
  a2 += __shfl_xor(a2, 32); a3 += __shfl_xor(a3, 32);
  if (half == 0){
    float4 b4 = *(const float4*)(bias + hl*4);
    float o0 = eluf(a0 + b4.x), o1 = eluf(a1 + b4.y);
    float o2 = eluf(a2 + b4.z), o3 = eluf(a3 + b4.w);
    float* fp = fea + (size_t)v*EMB + hl*4;
    float4 f = *(float4*)fp;
    float f0 = (f.x + o0)/3.0f, f1 = (f.y + o1)/3.0f;
    float f2 = (f.z + o2)/3.0f, f3 = (f.w + o3)/3.0f;
    *(float4*)fp = make_float4(f0, f1, f2, f3);
    uint2 sh;
    sh.x = bf16u(f0) | (bf16u(f1) << 16);
    sh.y = bf16u(f2) | (bf16u(f3) << 16);
    *(uint2*)(shadow + (size_t)v*64 + hl*2) = sh;
  }
}

// ================= score GEMM: dbuf, 16 j-tiles/block; pass0 self-reduces min/max =================
#define NT 16
template<int STORE>
__global__ __launch_bounds__(256) void k_score5(const ushort* __restrict__ Abf,
                                                const ushort* __restrict__ Bbf,
                                                float* __restrict__ S,
                                                float* __restrict__ mmpart){
  __shared__ __align__(16) uint8_t L0[32768];
  __shared__ __align__(16) uint8_t L1[32768];
  __shared__ float red[16];
  __shared__ unsigned sdone;
  const int t = threadIdx.x;
  const int lane = t & 63;
  const int w = t >> 6;
  const int wr = w >> 1, wc = w & 1;
  const int lr = lane & 15, lk = lane >> 4;
  const int i0b = blockIdx.y * 128;
  const int jbase = blockIdx.x * NT;

  stage128((const uint8_t*)(Abf + (size_t)i0b*EMB), L0, w, lane);
  stage128((const uint8_t*)(Bbf + (size_t)jbase*128*EMB), L1, w, lane);
  __syncthreads();

  short8 af[4][4];
  #pragma unroll
  for (int at = 0; at < 4; ++at){
    int ra = wr*64 + at*16 + lr;
    #pragma unroll
    for (int k0 = 0; k0 < 4; ++k0){
      int kb = k0*64 + lk*16;
      af[at][k0] = *(const short8*)&L0[ra*256 + (kb ^ ((ra & 7) << 4))];
    }
  }
  __syncthreads();
  stage128((const uint8_t*)(Bbf + (size_t)(jbase+1)*128*EMB), L0, w, lane);

  float mn = 0.f, sc = 0.f;
  if (STORE){
    mn = mmpart[0];
    float mx = mmpart[1];
    sc = (mx > mn) ? 1.0f/(mx - mn) : 0.0f;
  }
  float lmin = 3.4e38f, lmax = -3.4e38f;

  for (int jt = 0; jt < NT; ++jt){
    uint8_t* curB = (jt & 1) ? L0 : L1;
    f32x4 acc[4][4];
    #pragma unroll
    for (int a = 0; a < 4; ++a)
      #pragma unroll
      for (int b = 0; b < 4; ++b) acc[a][b] = (f32x4){0.f,0.f,0.f,0.f};

    #pragma unroll
    for (int k0 = 0; k0 < 4; ++k0){
      int kb = k0*64 + lk*16;
      short8 bfr[4];
      #pragma unroll
      for (int ct = 0; ct < 4; ++ct){
        int rb = wc*64 + ct*16 + lr;
        bfr[ct] = *(const short8*)&curB[rb*256 + (kb ^ ((rb & 7) << 4))];
      }
      #pragma unroll
      for (int at = 0; at < 4; ++at)
        #pragma unroll
        for (int ct = 0; ct < 4; ++ct)
          acc[at][ct] = __builtin_amdgcn_mfma_f32_16x16x32_bf16(af[at][k0], bfr[ct], acc[at][ct], 0, 0, 0);
    }

    int j0 = (jbase + jt)*128;
    if (STORE){
      #pragma unroll
      for (int at = 0; at < 4; ++at){
        #pragma unroll
        for (int ct = 0; ct < 4; ++ct){
          int colj = j0 + wc*64 + ct*16 + lr;
          int row0 = i0b + wr*64 + at*16 + lk*4;
          #pragma unroll
          for (int q = 0; q < 4; ++q){
            float vv = fminf(fmaxf((acc[at][ct][q] - mn)*sc, 0.f), 1.f);
            S[(size_t)(row0+q)*DIS_NN + colj] = vv;
          }
        }
      }
    } else {
      #pragma unroll
      for (int at = 0; at < 4; ++at)
        #pragma unroll
        for (int ct = 0; ct < 4; ++ct)
          #pragma unroll
          for (int q = 0; q < 4; ++q){
            float vv = acc[at][ct][q];
            lmin = fminf(lmin, vv); lmax = fmaxf(lmax, vv);
          }
    }
    __syncthreads();
    if (jt + 2 < NT)
      stage128((const uint8_t*)(Bbf + (size_t)(jbase+jt+2)*128*EMB), curB, w, lane);
  }

  if (!STORE){
    #pragma unroll
    for (int off = 32; off; off >>= 1){
      lmin = fminf(lmin, __shfl_xor(lmin, off));
      lmax = fmaxf(lmax, __shfl_xor(lmax, off));
    }
    if (lane == 0){ red[w*2] = lmin; red[w*2+1] = lmax; }
    __syncthreads();
    unsigned* ctr = (unsigned*)(mmpart + 1088);
    if (t == 0){
      float a = fminf(fminf(red[0], red[2]), fminf(red[4], red[6]));
      float b = fmaxf(fmaxf(red[1], red[3]), fmaxf(red[5], red[7]));
      int bid = blockIdx.y * 4 + blockIdx.x;
      mmpart[2 + bid*2]     = a;
      mmpart[2 + bid*2 + 1] = b;
      __threadfence();
      sdone = atomicAdd(ctr, 1u);
    }
    __syncthreads();
    if (sdone == 511u){
      __threadfence();
      float mnv = fminf(mmpart[2 + 2*t], mmpart[2 + 2*(t+256)]);
      float mxv = fmaxf(mmpart[3 + 2*t], mmpart[3 + 2*(t+256)]);
      #pragma unroll
      for (int off = 32; off; off >>= 1){
        mnv = fminf(mnv, __shfl_xor(mnv, off));
        mxv = fmaxf(mxv, __shfl_xor(mxv, off));
      }
      if (lane == 0){ red[w*2] = mnv; red[w*2+1] = mxv; }
      __syncthreads();
      if (t == 0){
        float a = fminf(fminf(red[0], red[2]), fminf(red[4], red[6]));
        float b = fmaxf(fmaxf(red[1], red[3]), fmaxf(red[5], red[7]));
        mmpart[0] = a; mmpart[1] = b;
      }
    }
  }
}

// ================= host =================
extern "C" void kernel_launch(void* const* d_in, const int* in_sizes, int n_in,
                              void* d_out, int out_size, void* d_ws, size_t ws_size,
                              hipStream_t stream){
  (void)in_sizes; (void)n_in; (void)out_size; (void)ws_size;
  const float* mm_x0  = (const float*)d_in[0];
  const float* dd_x0  = (const float*)d_in[1];
  const float* w1_mm  = (const float*)d_in[2];
  const float* b1_mm  = (const float*)d_in[3];
  const float* w2_mm  = (const float*)d_in[4];
  const float* b2_mm  = (const float*)d_in[5];
  const float* w3_mm  = (const float*)d_in[6];
  const float* asrc_mm= (const float*)d_in[7];
  const float* adst_mm= (const float*)d_in[8];
  const float* b3_mm  = (const float*)d_in[9];
  const float* w1_dd  = (const float*)d_in[10];
  const float* b1_dd  = (const float*)d_in[11];
  const float* w2_dd  = (const float*)d_in[12];
  const float* b2_dd  = (const float*)d_in[13];
  const float* w3_dd  = (const float*)d_in[14];
  const float* asrc_dd= (const float*)d_in[15];
  const float* adst_dd= (const float*)d_in[16];
  const float* b3_dd  = (const float*)d_in[17];
  const float* mm_ew  = (const float*)d_in[18];
  const float* dd_ew  = (const float*)d_in[19];
  const int* mm_edges = (const int*)d_in[20];
  const int* dd_edges = (const int*)d_in[21];

  float* S = (float*)d_out;
  float* p = S;
  ushort* Xm  = (ushort*)p; p += (size_t)MI_NN*EMB/2;
  ushort* Xd  = (ushort*)p; p += (size_t)DIS_NN*EMB/2;
  ushort* Hbm = (ushort*)p; p += (size_t)MI_NN*EMB/2;
  ushort* Hbd = (ushort*)p; p += (size_t)DIS_NN*EMB/2;
  ushort* WT  = (ushort*)p; p += 6*16384/2;
  float* DEG1m = p; p += MI_NN;
  float* DEG2m = p; p += MI_NN;
  float* ESm   = p; p += MI_NN;
  float* EDm   = p; p += MI_NN;
  float* DEG1d = p; p += DIS_NN;
  float* DEG2d = p; p += DIS_NN;
  float* ESd   = p; p += DIS_NN;
  float* EDd   = p; p += DIS_NN;
  int* CNTm  = (int*)p; p += MI_NN;
  int* CNTd  = (int*)p; p += DIS_NN;
  int* FILLm = (int*)p; p += MI_NN;
  int* FILLd = (int*)p; p += DIS_NN;
  int* RPm   = (int*)p; p += MI_NN + 64;
  int* RPd   = (int*)p; p += DIS_NN + 64;
  int2* EPKm = (int2*)p; p += (size_t)EMM*2;
  int2* EPKd = (int2*)p; p += (size_t)EDD*2;
  float* FEA_MI  = S + (size_t)MI_NN * DIS_NN;
  float* FEA_DIS = FEA_MI + (size_t)MI_NN*EMB;

  float* MM = (float*)d_ws;
  ushort* Abf = (ushort*)((char*)d_ws + 16384);
  ushort* Bbf = Abf + (size_t)MI_NN * EMB;

  const int* erow_m = mm_edges;
  const int* ecol_m = mm_edges + EMM;
  const int* erow_d = dd_edges;
  const int* ecol_d = dd_edges + EDD;

  // ---- prep: bf16 packs + W^T ----
  k_prep<<<1542, 256, 0, stream>>>(mm_x0, dd_x0, w1_mm, w2_mm, w3_mm,
                                   w1_dd, w2_dd, w3_dd, Xm, Xd, WT);
  // ---- CSR build ----
  hipMemsetAsync(CNTm, 0, (size_t)2*(MI_NN + DIS_NN)*sizeof(int), stream);
  k_count2g<<<EMM/256 + EDD/256, 256, 0, stream>>>(ecol_m, CNTm, EMM, EMM/256,
                                                   ecol_d, CNTd, EDD,
                                                   (unsigned*)(MM + 1088));
  k_scan2g<<<2, 1024, 0, stream>>>(CNTm, RPm, MI_NN, EMM, CNTd, RPd, DIS_NN, EDD);
  k_fill2g<<<EMM/256 + EDD/256, 256, 0, stream>>>(erow_m, ecol_m, mm_ew, RPm, FILLm, EPKm,
                                                  EMM, EMM/256,
                                                  erow_d, ecol_d, dd_ew, RPd, FILLd, EPKd,
                                                  EDD);
  const int GB = MI_NN/128 + DIS_NN/128;   // 192 mfma-gemm blocks
  const int AB = MI_NN/4 + DIS_NN/4;
  // ---- layer 1: GCN with edge weights ----
  k_gemm_mfma<0><<<GB, 256, 0, stream>>>(Xm, WT + 0*16384, Hbm, MI_NN/128,
                                         Xd, WT + 3*16384, Hbd,
                                         nullptr, nullptr, nullptr, nullptr,
                                         nullptr, nullptr, nullptr, nullptr);
  k_deg2g<<<AB, 256, 0, stream>>>(RPm, EPKm, DEG1m, DEG2m, MI_NN, MI_NN/4,
                                  RPd, EPKd, DEG1d, DEG2d, DIS_NN);
  k_agg2g<<<AB, 256, 0, stream>>>(Hbm, DEG1m, RPm, EPKm, b1_mm, Xm, FEA_MI, MI_NN, MI_NN/4,
                                  Hbd, DEG1d, RPd, EPKd, b1_dd, Xd, FEA_DIS, DIS_NN, 1, 0);
  // ---- layer 2: GCN, unit weights ----
  k_gemm_mfma<0><<<GB, 256, 0, stream>>>(Xm, WT + 1*16384, Hbm, MI_NN/128,
                                         Xd, WT + 4*16384, Hbd,
                                         nullptr, nullptr, nullptr, nullptr,
                                         nullptr, nullptr, nullptr, nullptr);
  k_agg2g<<<AB, 256, 0, stream>>>(Hbm, DEG2m, RPm, EPKm, b2_mm, Xm, FEA_MI, MI_NN, MI_NN/4,
                                  Hbd, DEG2d, RPd, EPKd, b2_dd, Xd, FEA_DIS, DIS_NN, 0, 1);
  // ---- layer 3: GAT (srcdst fused into gemm epilogue) ----
  k_gemm_mfma<1><<<GB, 256, 0, stream>>>(Xm, WT + 2*16384, Hbm, MI_NN/128,
                                         Xd, WT + 5*16384, Hbd,
                                         asrc_mm, adst_mm, ESm, EDm,
                                         asrc_dd, adst_dd, ESd, EDd);
  k_gat2g<<<AB, 256, 0, stream>>>(Hbm, ESm, EDm, RPm, EPKm, b3_mm, FEA_MI, (unsigned*)Abf, MI_NN, MI_NN/4,
                                  Hbd, ESd, EDd, RPd, EPKd, b3_dd, FEA_DIS, (unsigned*)Bbf, DIS_NN);
  // ---- score ----
  k_score5<0><<<dim3(DIS_NN/(128*NT), MI_NN/128), 256, 0, stream>>>(Abf, Bbf, nullptr, MM);
  k_score5<1><<<dim3(DIS_NN/(128*NT), MI_NN/128), 256, 0, stream>>>(Abf, Bbf, S, MM);
}